// Round 1
// baseline (586.392 us; speedup 1.0000x reference)
//
#include <hip/hip_runtime.h>

// PlasticSynapse elementwise update:
//   new_w = clip(baseline*ALPHA + w*(1-ALPHA)
//                + R[b] * |kappa[o,i]| * (post[b,o]*pre[b,i] + SIGMA*noise),
//                0, 1)
// Shapes: w,noise,out: (B,OUT,IN); baseline,kappa: (OUT,IN); pre: (B,IN);
//         post: (B,OUT); R: (B,1,1).  B=64, OUT=1024, IN=1024, all fp32.
//
// Memory-bound streaming kernel. HBM floor ~543 MB effective (L3 absorbs
// ~half the w/noise reads) -> ~90-100 us. Strategy: grid-stride with
// stride chosen so (o,i4) is invariant per thread -> hoist baseline/kappa
// loads + their math out of the loop; unroll 4 for deep MLP; nontemporal
// stores so the write-only 'out' stream doesn't evict w/noise from L2/L3.

constexpr int B_DIM  = 64;
constexpr int OUT_D  = 1024;
constexpr int IN_D   = 1024;
constexpr int IN4    = IN_D / 4;              // 256 float4 per row
constexpr int TOTAL4 = B_DIM * OUT_D * IN4;   // 16,777,216 float4
constexpr int BLOCK  = 256;
constexpr int GRID   = 2048;                  // 8192 waves = 32 waves/CU
constexpr int NTH    = BLOCK * GRID;          // 524,288 threads (stride)
constexpr int ITERS  = TOTAL4 / NTH;          // 32 iterations/thread

constexpr float ALPHA  = 0.01f;               // DT_W / TAU_W
constexpr float ONE_MA = 1.0f - ALPHA;        // 0.99
constexpr float SIGMA  = 0.14142135623730951f; // sqrt(2/ALPHA)*0.01

typedef float f32x4 __attribute__((ext_vector_type(4)));

__global__ __launch_bounds__(BLOCK)
void PlasticSynapse_69466801045994_kernel(
    const float4* __restrict__ w,
    const float4* __restrict__ baseline,
    const float*  __restrict__ R,
    const float4* __restrict__ pre,
    const float*  __restrict__ post,
    const float4* __restrict__ kappa,
    const float4* __restrict__ noise,
    float4*       __restrict__ out)
{
    const int tid = blockIdx.x * BLOCK + threadIdx.x;   // [0, 524288)

    // Decode (b0, o, i4) from tid. stride NTH = 2^19 float4 adds exactly
    // +2 to b each iteration (bits 18+ only) -> o, i4, oi are loop-invariant.
    const int i4  = tid & (IN4 - 1);          // bits 0..7
    const int bo0 = tid >> 8;                 // [0, 2048)
    const int o   = bo0 & (OUT_D - 1);        // bits 8..17
    const int b0  = bo0 >> 10;                // 0 or 1
    const int oi  = o * IN4 + i4;

    // Hoisted: loaded ONCE per thread (was 32x), plus their arithmetic.
    const float4 bl = baseline[oi];
    const float4 kp = kappa[oi];
    float4 blA, ak;
    blA.x = bl.x * ALPHA;  blA.y = bl.y * ALPHA;
    blA.z = bl.z * ALPHA;  blA.w = bl.w * ALPHA;
    ak.x  = fabsf(kp.x);   ak.y  = fabsf(kp.y);
    ak.z  = fabsf(kp.z);   ak.w  = fabsf(kp.w);

#pragma unroll 4
    for (int k = 0; k < ITERS; ++k) {
        const int idx = tid + k * NTH;        // walks the big streams
        const int b   = b0 + 2 * k;           // batch index for this step

        const float4 wv = w[idx];
        const float4 nv = noise[idx];
        const float4 pr = pre[b * IN4 + i4];
        const float  po = post[b * OUT_D + o];
        const float  r  = R[b];

        const float lrx = r * ak.x;
        const float lry = r * ak.y;
        const float lrz = r * ak.z;
        const float lrw = r * ak.w;

        float4 res;
        res.x = fminf(fmaxf(fmaf(lrx, fmaf(SIGMA, nv.x, po * pr.x),
                                 fmaf(wv.x, ONE_MA, blA.x)), 0.0f), 1.0f);
        res.y = fminf(fmaxf(fmaf(lry, fmaf(SIGMA, nv.y, po * pr.y),
                                 fmaf(wv.y, ONE_MA, blA.y)), 0.0f), 1.0f);
        res.z = fminf(fmaxf(fmaf(lrz, fmaf(SIGMA, nv.z, po * pr.z),
                                 fmaf(wv.z, ONE_MA, blA.z)), 0.0f), 1.0f);
        res.w = fminf(fmaxf(fmaf(lrw, fmaf(SIGMA, nv.w, po * pr.w),
                                 fmaf(wv.w, ONE_MA, blA.w)), 0.0f), 1.0f);

        // Write-only stream: nontemporal so it doesn't evict w/noise in L2/L3.
        __builtin_nontemporal_store(*(const f32x4*)&res, (f32x4*)&out[idx]);
    }
}

extern "C" void kernel_launch(void* const* d_in, const int* in_sizes, int n_in,
                              void* d_out, int out_size, void* d_ws, size_t ws_size,
                              hipStream_t stream) {
    // setup_inputs() dict order: w, baseline, R, pre, post, kappa, noise
    const float4* w        = (const float4*)d_in[0];
    const float4* baseline = (const float4*)d_in[1];
    const float*  R        = (const float*) d_in[2];
    const float4* pre      = (const float4*)d_in[3];
    const float*  post     = (const float*) d_in[4];
    const float4* kappa    = (const float4*)d_in[5];
    const float4* noise    = (const float4*)d_in[6];
    float4*       out      = (float4*)d_out;

    PlasticSynapse_69466801045994_kernel<<<GRID, BLOCK, 0, stream>>>(
        w, baseline, R, pre, post, kappa, noise, out);
}